// Round 1
// baseline (5458.597 us; speedup 1.0000x reference)
//
#include <hip/hip_runtime.h>
#include <hip/hip_bf16.h>
#include <math.h>

// Problem constants
#define KDIM 512
#define HEADS 8
#define NBLK 4
#define TSEQ 512
#define BATCH_ 4
#define ROWS (BATCH_ * TSEQ)          // 2048
#define DMODEL (KDIM * HEADS)         // 4096
#define VOCAB_ 32000
#define FFDIM (4 * KDIM)              // 2048

// ---------------------------------------------------------------------------
// Embedding + sinusoidal positional encoding
// h[row, c] = embed_W[x[row], c] + PE(t=row%T, c)
// PE(t, 2i) = sin(t / 10000^(i/128)), PE(t, 2i+1) = cos(...)
// ---------------------------------------------------------------------------
__global__ __launch_bounds__(256) void embed_pos_kernel(
    const int* __restrict__ x, const float* __restrict__ W, float* __restrict__ h)
{
    int idx = blockIdx.x * 256 + threadIdx.x;      // 0 .. ROWS*KDIM-1
    int row = idx >> 9;                            // /512
    int c = idx & 511;
    int tpos = row & (TSEQ - 1);
    int tok = x[row];
    int i = c >> 1;
    float inv = expf(-9.210340371976184f * ((float)i * (1.0f / 128.0f)));
    float ang = (float)tpos * inv;
    float pe = (c & 1) ? cosf(ang) : sinf(ang);
    h[idx] = W[(long long)tok * KDIM + c] + pe;
}

// ---------------------------------------------------------------------------
// Generic fp32 tiled GEMM: C = scale * (A @ B[^T]) [+ bias] [GELU] [causal mask]
// 64x64 tile, 16x16 threads, 4x4 per thread, K-step 16.
// Batched via blockIdx.z with two-level (batch, head) strides.
// All dims assumed multiples of 64 (K multiple of 16) -- true for this model.
// ---------------------------------------------------------------------------
template<bool TRANSB, bool BIAS, bool GELU, bool MASK>
__global__ __launch_bounds__(256) void gemm_f32(
    const float* __restrict__ A, const float* __restrict__ Bm,
    const float* __restrict__ bias, float* __restrict__ C,
    int M, int N, int Kd, int lda, int ldb, int ldc,
    long long aSB, long long aSH, long long bSB, long long bSH,
    long long cSB, long long cSH, int Hn, float scale)
{
    int zb = blockIdx.z / Hn, zh = blockIdx.z % Hn;
    A  += (long long)zb * aSB + (long long)zh * aSH;
    Bm += (long long)zb * bSB + (long long)zh * bSH;
    C  += (long long)zb * cSB + (long long)zh * cSH;

    int n0 = blockIdx.x * 64, m0 = blockIdx.y * 64;
    int tid = threadIdx.x;
    int tx = tid & 15, ty = tid >> 4;

    if (MASK && blockIdx.x > blockIdx.y) {
        // tile entirely above the diagonal -> all masked
        float4 o = make_float4(-1e30f, -1e30f, -1e30f, -1e30f);
        #pragma unroll
        for (int i = 0; i < 4; i++) {
            int m = m0 + ty * 4 + i;
            *(float4*)&C[(long long)m * ldc + n0 + tx * 4] = o;
        }
        return;
    }

    __shared__ float As[16][64];
    __shared__ float Bs[16][64];

    float acc[4][4] = {};

    int arow = tid >> 2;            // 0..63
    int acol = (tid & 3) * 4;       // 0,4,8,12

    for (int k0 = 0; k0 < Kd; k0 += 16) {
        // A tile (transposed into LDS: As[k][m])
        float4 av = *(const float4*)&A[(long long)(m0 + arow) * lda + k0 + acol];
        As[acol + 0][arow] = av.x;
        As[acol + 1][arow] = av.y;
        As[acol + 2][arow] = av.z;
        As[acol + 3][arow] = av.w;
        if (TRANSB) {
            float4 bv = *(const float4*)&Bm[(long long)(n0 + arow) * ldb + k0 + acol];
            Bs[acol + 0][arow] = bv.x;
            Bs[acol + 1][arow] = bv.y;
            Bs[acol + 2][arow] = bv.z;
            Bs[acol + 3][arow] = bv.w;
        } else {
            int brow = tid >> 4, bcol = (tid & 15) * 4;
            float4 bv = *(const float4*)&Bm[(long long)(k0 + brow) * ldb + n0 + bcol];
            *(float4*)&Bs[brow][bcol] = bv;
        }
        __syncthreads();
        #pragma unroll
        for (int kk = 0; kk < 16; ++kk) {
            float4 a = *(const float4*)&As[kk][ty * 4];
            float4 b = *(const float4*)&Bs[kk][tx * 4];
            float ar[4] = {a.x, a.y, a.z, a.w};
            float br[4] = {b.x, b.y, b.z, b.w};
            #pragma unroll
            for (int i = 0; i < 4; i++)
                #pragma unroll
                for (int j = 0; j < 4; j++)
                    acc[i][j] += ar[i] * br[j];
        }
        __syncthreads();
    }

    #pragma unroll
    for (int i = 0; i < 4; i++) {
        int m = m0 + ty * 4 + i;
        float4 o;
        float* op = &o.x;
        #pragma unroll
        for (int j = 0; j < 4; j++) {
            int n = n0 + tx * 4 + j;
            float v = acc[i][j] * scale;
            if (BIAS) v += bias[n];
            if (GELU) v = 0.5f * v * (1.0f + erff(v * 0.70710678118654752f));
            if (MASK && n > m) v = -1e30f;
            op[j] = v;
        }
        *(float4*)&C[(long long)m * ldc + n0 + tx * 4] = o;
    }
}

// ---------------------------------------------------------------------------
// LayerNorm over 512 columns, one wave (64 threads) per row.
// out = (A[+R] - mean) / sqrt(var + eps) * w + b   (two-pass, matches ref)
// ---------------------------------------------------------------------------
template<bool RES>
__global__ __launch_bounds__(64) void ln512(
    const float* __restrict__ A, const float* __restrict__ R,
    const float* __restrict__ w, const float* __restrict__ bias,
    float* __restrict__ out)
{
    long long row = blockIdx.x;
    int t = threadIdx.x;
    const float* a = A + row * KDIM;
    float4 u0 = *(const float4*)&a[t * 4];
    float4 u1 = *(const float4*)&a[256 + t * 4];
    if (RES) {
        const float* r = R + row * KDIM;
        float4 r0 = *(const float4*)&r[t * 4];
        float4 r1 = *(const float4*)&r[256 + t * 4];
        u0.x += r0.x; u0.y += r0.y; u0.z += r0.z; u0.w += r0.w;
        u1.x += r1.x; u1.y += r1.y; u1.z += r1.z; u1.w += r1.w;
    }
    float xv[8] = {u0.x, u0.y, u0.z, u0.w, u1.x, u1.y, u1.z, u1.w};
    float s = 0.f;
    #pragma unroll
    for (int e = 0; e < 8; e++) s += xv[e];
    #pragma unroll
    for (int off = 32; off; off >>= 1) s += __shfl_xor(s, off);
    float mean = s * (1.0f / 512.0f);
    float vs = 0.f;
    #pragma unroll
    for (int e = 0; e < 8; e++) { float d = xv[e] - mean; vs += d * d; }
    #pragma unroll
    for (int off = 32; off; off >>= 1) vs += __shfl_xor(vs, off);
    float rstd = rsqrtf(vs * (1.0f / 512.0f) + 1e-5f);

    int c0 = t * 4, c1 = 256 + t * 4;
    float4 w0 = *(const float4*)&w[c0], w1 = *(const float4*)&w[c1];
    float4 b0 = *(const float4*)&bias[c0], b1 = *(const float4*)&bias[c1];
    float4 o0, o1;
    o0.x = (xv[0] - mean) * rstd * w0.x + b0.x;
    o0.y = (xv[1] - mean) * rstd * w0.y + b0.y;
    o0.z = (xv[2] - mean) * rstd * w0.z + b0.z;
    o0.w = (xv[3] - mean) * rstd * w0.w + b0.w;
    o1.x = (xv[4] - mean) * rstd * w1.x + b1.x;
    o1.y = (xv[5] - mean) * rstd * w1.y + b1.y;
    o1.z = (xv[6] - mean) * rstd * w1.z + b1.z;
    o1.w = (xv[7] - mean) * rstd * w1.w + b1.w;
    *(float4*)&out[row * KDIM + c0] = o0;
    *(float4*)&out[row * KDIM + c1] = o1;
}

// ---------------------------------------------------------------------------
// Row softmax over 512 entries (in-place), one wave per row.
// Masked entries arrive as -1e30 -> exp underflows to 0 (matches -inf mask).
// ---------------------------------------------------------------------------
__global__ __launch_bounds__(64) void softmax512(float* __restrict__ S)
{
    long long base = (long long)blockIdx.x * 512;
    int t = threadIdx.x;
    float4 u0 = *(const float4*)&S[base + t * 4];
    float4 u1 = *(const float4*)&S[base + 256 + t * 4];
    float xv[8] = {u0.x, u0.y, u0.z, u0.w, u1.x, u1.y, u1.z, u1.w};
    float m = xv[0];
    #pragma unroll
    for (int e = 1; e < 8; e++) m = fmaxf(m, xv[e]);
    #pragma unroll
    for (int off = 32; off; off >>= 1) m = fmaxf(m, __shfl_xor(m, off));
    float s = 0.f;
    #pragma unroll
    for (int e = 0; e < 8; e++) { xv[e] = expf(xv[e] - m); s += xv[e]; }
    #pragma unroll
    for (int off = 32; off; off >>= 1) s += __shfl_xor(s, off);
    float inv = 1.0f / s;
    float4 o0 = make_float4(xv[0] * inv, xv[1] * inv, xv[2] * inv, xv[3] * inv);
    float4 o1 = make_float4(xv[4] * inv, xv[5] * inv, xv[6] * inv, xv[7] * inv);
    *(float4*)&S[base + t * 4] = o0;
    *(float4*)&S[base + 256 + t * 4] = o1;
}

// ---------------------------------------------------------------------------
extern "C" void kernel_launch(void* const* d_in, const int* in_sizes, int n_in,
                              void* d_out, int out_size, void* d_ws, size_t ws_size,
                              hipStream_t stream)
{
    const int*   x       = (const int*)  d_in[0];
    const float* embedW  = (const float*)d_in[1];
    const float* Wq      = (const float*)d_in[2];
    const float* Wk      = (const float*)d_in[3];
    const float* Wv      = (const float*)d_in[4];
    const float* Wu      = (const float*)d_in[5];
    const float* bu      = (const float*)d_in[6];
    const float* W1      = (const float*)d_in[7];
    const float* b1      = (const float*)d_in[8];
    const float* W2      = (const float*)d_in[9];
    const float* b2      = (const float*)d_in[10];
    const float* ln1w    = (const float*)d_in[11];
    const float* ln1b    = (const float*)d_in[12];
    const float* ln2w    = (const float*)d_in[13];
    const float* ln2b    = (const float*)d_in[14];
    const float* lnfw    = (const float*)d_in[15];
    const float* lnfb    = (const float*)d_in[16];
    const float* unembW  = (const float*)d_in[17];
    const float* unembB  = (const float*)d_in[18];

    float* out = (float*)d_out;
    float* wsf = (float*)d_ws;

    // Scratch layout inside d_out (65,536,000 floats total; all dead before
    // the final unembed GEMM rewrites the full output):
    const long long QKV = (long long)ROWS * DMODEL;    // 8,388,608 floats
    float* q    = out;                                  // [2048,4096]
    float* kbuf = out + QKV;                            // [2048,4096]
    float* v    = out + 2 * QKV;                        // [2048,4096]
    float* sc   = out + 3 * QKV;                        // [4,8,512,512]
    float* y    = out + 4 * QKV;                        // [2048,4096]
    float* f1   = out + 5 * QKV;                        // [2048,2048] (ffn1); first 1M floats double as tmp512
    float* tmp512 = f1;                                 // [2048,512] attention out-proj (dead before f1 written)
    float* ff2  = q;                                    // [2048,512] reuse q region (dead by then)

    // Persistent h buffers must survive the final GEMM -> live in d_ws (8.4 MB)
    float* hbuf = wsf;                                  // [2048,512]
    float* h2   = wsf + (long long)ROWS * KDIM;         // [2048,512]

    const float invsqrt = 0.04419417382415922f;         // 1/sqrt(512)
    const long long zz = 0;

    embed_pos_kernel<<<ROWS * KDIM / 256, 256, 0, stream>>>(x, embedW, hbuf);

    for (int i = 0; i < NBLK; i++) {
        const float* Wq_i = Wq + (long long)i * KDIM * DMODEL;
        const float* Wk_i = Wk + (long long)i * KDIM * DMODEL;
        const float* Wv_i = Wv + (long long)i * KDIM * DMODEL;
        const float* Wu_i = Wu + (long long)i * DMODEL * KDIM;
        const float* bu_i = bu + (long long)i * KDIM;
        const float* W1_i = W1 + (long long)i * KDIM * FFDIM;
        const float* b1_i = b1 + (long long)i * FFDIM;
        const float* W2_i = W2 + (long long)i * FFDIM * KDIM;
        const float* b2_i = b2 + (long long)i * KDIM;
        const float* l1w = ln1w + i * KDIM, *l1b = ln1b + i * KDIM;
        const float* l2w = ln2w + i * KDIM, *l2b = ln2b + i * KDIM;

        // QKV projections: [2048,512] @ [512,4096]
        gemm_f32<false,false,false,false><<<dim3(64,32,1),256,0,stream>>>(
            hbuf, Wq_i, nullptr, q, ROWS, DMODEL, KDIM, KDIM, DMODEL, DMODEL,
            zz,zz,zz,zz,zz,zz, 1, 1.0f);
        gemm_f32<false,false,false,false><<<dim3(64,32,1),256,0,stream>>>(
            hbuf, Wk_i, nullptr, kbuf, ROWS, DMODEL, KDIM, KDIM, DMODEL, DMODEL,
            zz,zz,zz,zz,zz,zz, 1, 1.0f);
        gemm_f32<false,false,false,false><<<dim3(64,32,1),256,0,stream>>>(
            hbuf, Wv_i, nullptr, v, ROWS, DMODEL, KDIM, KDIM, DMODEL, DMODEL,
            zz,zz,zz,zz,zz,zz, 1, 1.0f);

        // scores[b,h,qi,si] = (Q . K) / sqrt(512), causal mask
        gemm_f32<true,false,false,true><<<dim3(8,8,BATCH_*HEADS),256,0,stream>>>(
            q, kbuf, nullptr, sc, TSEQ, TSEQ, KDIM, DMODEL, DMODEL, TSEQ,
            (long long)TSEQ*DMODEL, (long long)KDIM,
            (long long)TSEQ*DMODEL, (long long)KDIM,
            (long long)HEADS*TSEQ*TSEQ, (long long)TSEQ*TSEQ, HEADS, invsqrt);

        softmax512<<<BATCH_*HEADS*TSEQ, 64, 0, stream>>>(sc);

        // y[b,qi,h,:] = P @ V
        gemm_f32<false,false,false,false><<<dim3(8,8,BATCH_*HEADS),256,0,stream>>>(
            sc, v, nullptr, y, TSEQ, KDIM, TSEQ, TSEQ, DMODEL, DMODEL,
            (long long)HEADS*TSEQ*TSEQ, (long long)TSEQ*TSEQ,
            (long long)TSEQ*DMODEL, (long long)KDIM,
            (long long)TSEQ*DMODEL, (long long)KDIM, HEADS, 1.0f);

        // attention out-proj: [2048,4096] @ [4096,512] + bu
        gemm_f32<false,true,false,false><<<dim3(8,32,1),256,0,stream>>>(
            y, Wu_i, bu_i, tmp512, ROWS, KDIM, DMODEL, DMODEL, KDIM, KDIM,
            zz,zz,zz,zz,zz,zz, 1, 1.0f);

        // h2 = LN(tmp512 + hbuf)
        ln512<true><<<ROWS, 64, 0, stream>>>(tmp512, hbuf, l1w, l1b, h2);

        // ffn1 = gelu(h2 @ W1 + b1): [2048,512]@[512,2048]
        gemm_f32<false,true,true,false><<<dim3(32,32,1),256,0,stream>>>(
            h2, W1_i, b1_i, f1, ROWS, FFDIM, KDIM, KDIM, FFDIM, FFDIM,
            zz,zz,zz,zz,zz,zz, 1, 1.0f);

        // ff2 = ffn1 @ W2 + b2: [2048,2048]@[2048,512]
        gemm_f32<false,true,false,false><<<dim3(8,32,1),256,0,stream>>>(
            f1, W2_i, b2_i, ff2, ROWS, KDIM, FFDIM, FFDIM, KDIM, KDIM,
            zz,zz,zz,zz,zz,zz, 1, 1.0f);

        // hbuf = LN(ff2 + h2)
        ln512<true><<<ROWS, 64, 0, stream>>>(ff2, h2, l2w, l2b, hbuf);
    }

    // final LN
    ln512<false><<<ROWS, 64, 0, stream>>>(hbuf, nullptr, lnfw, lnfb, h2);

    // unembed: [2048,512] @ [512,32000] + b -> full d_out
    gemm_f32<false,true,false,false><<<dim3(VOCAB_/64,32,1),256,0,stream>>>(
        h2, unembW, unembB, out, ROWS, VOCAB_, KDIM, KDIM, VOCAB_, VOCAB_,
        zz,zz,zz,zz,zz,zz, 1, 1.0f);
}

// Round 2
// 1456.880 us; speedup vs baseline: 3.7468x; 3.7468x over previous
//
#include <hip/hip_runtime.h>
#include <math.h>
#include <stdint.h>

#define KDIM 512
#define HEADS 8
#define NBLK 4
#define TSEQ 512
#define BATCH_ 4
#define ROWS 2048
#define DMODEL 4096
#define VOCAB_ 32000
#define FFDIM 2048

typedef __attribute__((ext_vector_type(4))) float f32x4;
typedef __attribute__((ext_vector_type(8))) short s16x8;
typedef unsigned short u16t;

// fp32 -> bf16 round-to-nearest-even
__device__ __forceinline__ u16t f2bf(float f) {
    union { float f; unsigned u; } cv; cv.f = f;
    return (u16t)((cv.u + 0x7FFFu + ((cv.u >> 16) & 1u)) >> 16);
}

// async 16B global -> LDS (wave-uniform LDS base + lane*16). CK-style casts.
__device__ __forceinline__ void gload_lds16(const void* g, void* lds) {
    __builtin_amdgcn_global_load_lds(
        (const __attribute__((address_space(1))) unsigned int*)(uintptr_t)g,
        (__attribute__((address_space(3))) unsigned int*)(unsigned int)(uintptr_t)lds,
        16, 0, 0);
}

// ---------------------------------------------------------------------------
// bf16 MFMA GEMM, TRANSB form: C[m][n] = scale * sum_k A[m][k] * Bt[n][k]
// A: [M x K] bf16 row-major (lda), Bt: [N x K] bf16 row-major (ldb).
// BM x BN tile, 256 threads = 4 waves (2x2), each wave BM/2 x BN/2 via
// 16x16x32 MFMAs. BK=32. LDS staged via global_load_lds(16B) with XOR swizzle
// on the 16B k-chunk slot: phys = kc ^ ((row>>1)&3)  -> frag ds_read_b128 is
// 2-way bank aliased (free on CDNA4).
// Batched over blockIdx.z with (zb, zh) two-level strides.
// ---------------------------------------------------------------------------
template<int BM, int BN, bool OUTBF, bool BIAS, bool GELU, bool MASK, bool KTRI>
__global__ __launch_bounds__(256, 2) void gemm_bf16(
    const u16t* __restrict__ A, const u16t* __restrict__ Bt,
    const float* __restrict__ bias, void* __restrict__ Cv,
    int Kd, int lda, int ldb, int ldc,
    long long aSB, long long aSH, long long bSB, long long bSH,
    long long cSB, long long cSH, int Hn, float scale)
{
    const int zb = blockIdx.z / Hn, zh = blockIdx.z % Hn;
    A  += zb * aSB + zh * aSH;
    Bt += zb * bSB + zh * bSH;
    const int m0 = blockIdx.y * BM, n0 = blockIdx.x * BN;
    const int tid = threadIdx.x;
    const int wave = tid >> 6, lane = tid & 63;
    const int quad = lane >> 4, l15 = lane & 15;
    const int wm = (wave >> 1) * (BM / 2), wn = (wave & 1) * (BN / 2);
    constexpr int MT = BM / 32, NT = BN / 32;

    if (MASK && n0 > m0) {           // tile entirely above diagonal
        float* C = (float*)Cv + zb * cSB + zh * cSH;
        for (int e = tid; e < BM * BN; e += 256) {
            int r = e / BN, c = e % BN;
            C[(long long)(m0 + r) * ldc + n0 + c] = -1e30f;
        }
        return;
    }

    __shared__ __align__(16) u16t As[BM * 32];
    __shared__ __align__(16) u16t Bs[BN * 32];

    f32x4 acc[MT][NT];
    #pragma unroll
    for (int i = 0; i < MT; i++)
        #pragma unroll
        for (int j = 0; j < NT; j++)
            acc[i][j] = (f32x4){0.f, 0.f, 0.f, 0.f};

    const int kend = KTRI ? (Kd < m0 + BM ? Kd : m0 + BM) : Kd;

    for (int k0 = 0; k0 < kend; k0 += 32) {
        #pragma unroll
        for (int r = 0; r < BM / 64; ++r) {
            int cc = r * 256 + tid;
            int row = cc >> 2, ps = cc & 3;
            int kc = ps ^ ((row >> 1) & 3);
            gload_lds16(A + (long long)(m0 + row) * lda + k0 + kc * 8, &As[cc * 8]);
        }
        #pragma unroll
        for (int r = 0; r < BN / 64; ++r) {
            int cc = r * 256 + tid;
            int row = cc >> 2, ps = cc & 3;
            int kc = ps ^ ((row >> 1) & 3);
            gload_lds16(Bt + (long long)(n0 + row) * ldb + k0 + kc * 8, &Bs[cc * 8]);
        }
        __syncthreads();   // drains vmcnt for the LDS DMA

        s16x8 af[MT], bfr[NT];
        #pragma unroll
        for (int i = 0; i < MT; i++) {
            int row = wm + i * 16 + l15;
            int ps = quad ^ ((row >> 1) & 3);
            af[i] = *(const s16x8*)&As[row * 32 + ps * 8];
        }
        #pragma unroll
        for (int j = 0; j < NT; j++) {
            int row = wn + j * 16 + l15;
            int ps = quad ^ ((row >> 1) & 3);
            bfr[j] = *(const s16x8*)&Bs[row * 32 + ps * 8];
        }
        #pragma unroll
        for (int i = 0; i < MT; i++)
            #pragma unroll
            for (int j = 0; j < NT; j++)
                acc[i][j] = __builtin_amdgcn_mfma_f32_16x16x32_bf16(
                    af[i], bfr[j], acc[i][j], 0, 0, 0);
        __syncthreads();
    }

    // epilogue: C/D layout col=lane&15, row=quad*4+reg
    const long long cb = zb * cSB + zh * cSH;
    #pragma unroll
    for (int i = 0; i < MT; i++) {
        #pragma unroll
        for (int j = 0; j < NT; j++) {
            const int col = n0 + wn + j * 16 + l15;
            #pragma unroll
            for (int r = 0; r < 4; r++) {
                const int row = m0 + wm + i * 16 + quad * 4 + r;
                float v = acc[i][j][r] * scale;
                if (BIAS) v += bias[col];
                if (GELU) v = 0.5f * v * (1.0f + erff(v * 0.70710678118654752f));
                if (MASK && col > row) v = -1e30f;
                if (OUTBF) ((u16t*)Cv)[cb + (long long)row * ldc + col] = f2bf(v);
                else       ((float*)Cv)[cb + (long long)row * ldc + col] = v;
            }
        }
    }
}

// ---------------------------------------------------------------------------
// fp32 W[K][N] (ldw) -> bf16 WT[N][K] (ldt), 32x32 LDS-tiled transpose+convert
// ---------------------------------------------------------------------------
__global__ __launch_bounds__(256) void wconvT(
    const float* __restrict__ W, int ldw, int n_off, long long srcZ,
    u16t* __restrict__ WT, int ldt, long long dstZ)
{
    W  += (long long)blockIdx.z * srcZ;
    WT += (long long)blockIdx.z * dstZ;
    __shared__ float t[32][33];
    const int n0 = blockIdx.x * 32, k0 = blockIdx.y * 32;
    const int c = threadIdx.x & 31, r = threadIdx.x >> 5;
    #pragma unroll
    for (int i = 0; i < 4; i++)
        t[r + i * 8][c] = W[(long long)(k0 + r + i * 8) * ldw + n_off + n0 + c];
    __syncthreads();
    #pragma unroll
    for (int i = 0; i < 4; i++)
        WT[(long long)(n0 + r + i * 8) * ldt + k0 + c] = f2bf(t[c][r + i * 8]);
}

// ---------------------------------------------------------------------------
// Embedding + sinusoidal positional encoding -> fp32 h and bf16 hb
// ---------------------------------------------------------------------------
__global__ __launch_bounds__(256) void embed_pos(
    const int* __restrict__ x, const float* __restrict__ W,
    float* __restrict__ h, u16t* __restrict__ hb)
{
    int idx = blockIdx.x * 256 + threadIdx.x;
    int row = idx >> 9, c = idx & 511;
    int tpos = row & (TSEQ - 1);
    int tok = x[row];
    int i = c >> 1;
    float inv = expf(-9.210340371976184f * ((float)i * (1.0f / 128.0f)));
    float ang = (float)tpos * inv;
    float pe = (c & 1) ? cosf(ang) : sinf(ang);
    float v = W[(long long)tok * KDIM + c] + pe;
    h[idx] = v;
    hb[idx] = f2bf(v);
}

// ---------------------------------------------------------------------------
// LayerNorm over 512, one wave per row; writes fp32 out and bf16 outb
// ---------------------------------------------------------------------------
template<bool RES>
__global__ __launch_bounds__(64) void ln512(
    const float* __restrict__ A, const float* __restrict__ R,
    const float* __restrict__ w, const float* __restrict__ bias,
    float* __restrict__ out, u16t* __restrict__ outb)
{
    long long row = blockIdx.x;
    int t = threadIdx.x;
    const float* a = A + row * KDIM;
    float4 u0 = *(const float4*)&a[t * 4];
    float4 u1 = *(const float4*)&a[256 + t * 4];
    if (RES) {
        const float* rr = R + row * KDIM;
        float4 r0 = *(const float4*)&rr[t * 4];
        float4 r1 = *(const float4*)&rr[256 + t * 4];
        u0.x += r0.x; u0.y += r0.y; u0.z += r0.z; u0.w += r0.w;
        u1.x += r1.x; u1.y += r1.y; u1.z += r1.z; u1.w += r1.w;
    }
    float xv[8] = {u0.x, u0.y, u0.z, u0.w, u1.x, u1.y, u1.z, u1.w};
    float s = 0.f;
    #pragma unroll
    for (int e = 0; e < 8; e++) s += xv[e];
    #pragma unroll
    for (int off = 32; off; off >>= 1) s += __shfl_xor(s, off);
    float mean = s * (1.0f / 512.0f);
    float vs = 0.f;
    #pragma unroll
    for (int e = 0; e < 8; e++) { float d = xv[e] - mean; vs += d * d; }
    #pragma unroll
    for (int off = 32; off; off >>= 1) vs += __shfl_xor(vs, off);
    float rstd = rsqrtf(vs * (1.0f / 512.0f) + 1e-5f);

    int c0 = t * 4, c1 = 256 + t * 4;
    #pragma unroll
    for (int e = 0; e < 8; e++) {
        int c = (e < 4) ? (c0 + e) : (c1 + e - 4);
        float o = (xv[e] - mean) * rstd * w[c] + bias[c];
        out[row * KDIM + c] = o;
        outb[row * KDIM + c] = f2bf(o);
    }
}

// ---------------------------------------------------------------------------
// Row softmax over 512 (fp32 in -> bf16 out), one wave per row
// ---------------------------------------------------------------------------
__global__ __launch_bounds__(64) void softmax512b(
    const float* __restrict__ S, u16t* __restrict__ P)
{
    long long base = (long long)blockIdx.x * 512;
    int t = threadIdx.x;
    float4 u0 = *(const float4*)&S[base + t * 4];
    float4 u1 = *(const float4*)&S[base + 256 + t * 4];
    float xv[8] = {u0.x, u0.y, u0.z, u0.w, u1.x, u1.y, u1.z, u1.w};
    float m = xv[0];
    #pragma unroll
    for (int e = 1; e < 8; e++) m = fmaxf(m, xv[e]);
    #pragma unroll
    for (int off = 32; off; off >>= 1) m = fmaxf(m, __shfl_xor(m, off));
    float s = 0.f;
    #pragma unroll
    for (int e = 0; e < 8; e++) { xv[e] = expf(xv[e] - m); s += xv[e]; }
    #pragma unroll
    for (int off = 32; off; off >>= 1) s += __shfl_xor(s, off);
    float inv = 1.0f / s;
    #pragma unroll
    for (int e = 0; e < 8; e++) {
        int c = (e < 4) ? (t * 4 + e) : (256 + t * 4 + e - 4);
        P[base + c] = f2bf(xv[e] * inv);
    }
}

// ---------------------------------------------------------------------------
extern "C" void kernel_launch(void* const* d_in, const int* in_sizes, int n_in,
                              void* d_out, int out_size, void* d_ws, size_t ws_size,
                              hipStream_t stream)
{
    const int*   x      = (const int*)  d_in[0];
    const float* embedW = (const float*)d_in[1];
    const float* Wq     = (const float*)d_in[2];
    const float* Wk     = (const float*)d_in[3];
    const float* Wv     = (const float*)d_in[4];
    const float* Wu     = (const float*)d_in[5];
    const float* bu     = (const float*)d_in[6];
    const float* W1     = (const float*)d_in[7];
    const float* b1     = (const float*)d_in[8];
    const float* W2     = (const float*)d_in[9];
    const float* b2     = (const float*)d_in[10];
    const float* ln1w   = (const float*)d_in[11];
    const float* ln1b   = (const float*)d_in[12];
    const float* ln2w   = (const float*)d_in[13];
    const float* ln2b   = (const float*)d_in[14];
    const float* lnfw   = (const float*)d_in[15];
    const float* lnfb   = (const float*)d_in[16];
    const float* unembW = (const float*)d_in[17];
    const float* unembB = (const float*)d_in[18];

    char* ob = (char*)d_out;
    float* outF = (float*)d_out;

    // ---- d_out scratch layout (bytes). All dead before the final 5 unembed
    // GEMMs overwrite d_out column-chunk by column-chunk.
    u16t*  wb  = (u16t*)(ob);                  // bf16^T weights, 4 x 10,485,760 u16
    u16t*  qk  = (u16t*)(ob + 83886080);       // [2048 x 8192] bf16 (Q|K fused)
    u16t*  vt  = (u16t*)(ob + 117440512);      // [4096 x 2048] bf16 (V^T)
    float* sc  = (float*)(ob + 134217728);     // [32 x 512 x 512] fp32 scores
    u16t*  Pb  = (u16t*) (ob + 167772160);     // [32 x 512 x 512] bf16 probs
    u16t*  y   = (u16t*) (ob + 184549376);     // [2048 x 4096] bf16
    u16t*  f1  = (u16t*) (ob + 201326592);     // [2048 x 2048] bf16
    float* tmp = (float*)(ob + 209715200);     // [2048 x 512] fp32
    float* ff2 = (float*)(ob + 213909504);     // [2048 x 512] fp32
    float* h   = (float*)(ob + 218103808);     // [2048 x 512] fp32 residual
    float* h2  = (float*)(ob + 222298112);     // [2048 x 512] fp32
    u16t*  hb  = (u16t*) (ob + 226492416);     // bf16 of h
    u16t*  h2b = (u16t*) (ob + 228589568);     // bf16 of h2   (end 230,686,720)

    // ---- d_ws: only what must survive the final GEMMs (8.65 MB)
    char* wsb = (char*)d_ws;
    u16t* hf  = (u16t*)(wsb);                  // [2048 x 512] bf16 final-LN
    u16t* wun = (u16t*)(wsb + 2097152);        // [6400 x 512] bf16 unembed chunk

    // per-block bf16^T weight offsets (u16 elements)
    const long long WBLK = 10485760;
    const long long OQ = 0, OK_ = 2097152, OV = 4194304, OU = 6291456,
                    O1 = 8388608, O2 = 9437184;

    const float inv_sqrt_k = 0.04419417382415922f;
    const long long z0 = 0;

    // ---- weight convert+transpose (all blocks batched via grid.z) ----
    wconvT<<<dim3(DMODEL/32, KDIM/32, NBLK), 256, 0, stream>>>(
        Wq, DMODEL, 0, (long long)KDIM*DMODEL, wb + OQ, KDIM, WBLK);
    wconvT<<<dim3(DMODEL/32, KDIM/32, NBLK), 256, 0, stream>>>(
        Wk, DMODEL, 0, (long long)KDIM*DMODEL, wb + OK_, KDIM, WBLK);
    wconvT<<<dim3(DMODEL/32, KDIM/32, NBLK), 256, 0, stream>>>(
        Wv, DMODEL, 0, (long long)KDIM*DMODEL, wb + OV, KDIM, WBLK);
    wconvT<<<dim3(KDIM/32, DMODEL/32, NBLK), 256, 0, stream>>>(
        Wu, KDIM, 0, (long long)DMODEL*KDIM, wb + OU, DMODEL, WBLK);
    wconvT<<<dim3(FFDIM/32, KDIM/32, NBLK), 256, 0, stream>>>(
        W1, FFDIM, 0, (long long)KDIM*FFDIM, wb + O1, KDIM, WBLK);
    wconvT<<<dim3(KDIM/32, FFDIM/32, NBLK), 256, 0, stream>>>(
        W2, KDIM, 0, (long long)FFDIM*KDIM, wb + O2, FFDIM, WBLK);

    embed_pos<<<ROWS * KDIM / 256, 256, 0, stream>>>(x, embedW, h, hb);

    for (int i = 0; i < NBLK; i++) {
        u16t* wbi = wb + (long long)i * WBLK;

        // QK fused: [2048x512] @ [512x8192] -> qk bf16
        gemm_bf16<128,128,true,false,false,false,false>
            <<<dim3(64, 16, 1), 256, 0, stream>>>(
            hb, wbi + OQ, nullptr, qk, KDIM, KDIM, KDIM, 2*DMODEL,
            z0,z0,z0,z0,z0,z0, 1, 1.0f);

        // V^T = WvT @ h^T: [4096x512] x [2048x512]^T -> vt bf16 [4096x2048]
        gemm_bf16<128,128,true,false,false,false,false>
            <<<dim3(16, 32, 1), 256, 0, stream>>>(
            wbi + OV, hb, nullptr, vt, KDIM, KDIM, KDIM, ROWS,
            z0,z0,z0,z0,z0,z0, 1, 1.0f);

        // scores = Q K^T / sqrt(512), causal  (per b,h) -> sc fp32
        gemm_bf16<128,128,false,false,false,true,false>
            <<<dim3(4, 4, BATCH_*HEADS), 256, 0, stream>>>(
            qk, qk + DMODEL, nullptr, sc, KDIM, 2*DMODEL, 2*DMODEL, TSEQ,
            (long long)TSEQ*2*DMODEL, (long long)KDIM,
            (long long)TSEQ*2*DMODEL, (long long)KDIM,
            (long long)HEADS*TSEQ*TSEQ, (long long)TSEQ*TSEQ, HEADS, inv_sqrt_k);

        softmax512b<<<BATCH_*HEADS*TSEQ, 64, 0, stream>>>(sc, Pb);

        // y = P @ V  (per b,h), triangular K-limit -> y bf16 [2048x4096]
        gemm_bf16<128,128,true,false,false,false,true>
            <<<dim3(4, 4, BATCH_*HEADS), 256, 0, stream>>>(
            Pb, vt, nullptr, y, TSEQ, TSEQ, ROWS, DMODEL,
            (long long)HEADS*TSEQ*TSEQ, (long long)TSEQ*TSEQ,
            (long long)TSEQ, (long long)TSEQ*ROWS,
            (long long)TSEQ*DMODEL, (long long)KDIM, HEADS, 1.0f);

        // out-proj: [2048x4096] @ [4096x512] + bu -> tmp fp32 (64-tile: 256 blocks)
        gemm_bf16<64,64,false,true,false,false,false>
            <<<dim3(8, 32, 1), 256, 0, stream>>>(
            y, wbi + OU, bu + i*KDIM, tmp, DMODEL, DMODEL, DMODEL, KDIM,
            z0,z0,z0,z0,z0,z0, 1, 1.0f);

        ln512<true><<<ROWS, 64, 0, stream>>>(
            tmp, h, ln1w + i*KDIM, ln1b + i*KDIM, h2, h2b);

        // ffn1 = gelu(h2 @ W1 + b1) -> f1 bf16 [2048x2048]
        gemm_bf16<128,128,true,true,true,false,false>
            <<<dim3(16, 16, 1), 256, 0, stream>>>(
            h2b, wbi + O1, b1 + i*FFDIM, f1, KDIM, KDIM, KDIM, FFDIM,
            z0,z0,z0,z0,z0,z0, 1, 1.0f);

        // ffn2 = f1 @ W2 + b2 -> ff2 fp32 (64-tile)
        gemm_bf16<64,64,false,true,false,false,false>
            <<<dim3(8, 32, 1), 256, 0, stream>>>(
            f1, wbi + O2, b2 + i*KDIM, ff2, FFDIM, FFDIM, FFDIM, KDIM,
            z0,z0,z0,z0,z0,z0, 1, 1.0f);

        ln512<true><<<ROWS, 64, 0, stream>>>(
            ff2, h2, ln2w + i*KDIM, ln2b + i*KDIM, h, hb);
    }

    // final LN (fp32 out goes to dead tmp; hf bf16 is what we need)
    ln512<false><<<ROWS, 64, 0, stream>>>(h, nullptr, lnfw, lnfb, tmp, hf);

    // unembed in 5 column chunks of 6400 (weight chunk converted into ws)
    const int CH = 6400;
    for (int c = 0; c < 5; c++) {
        wconvT<<<dim3(CH/32, KDIM/32, 1), 256, 0, stream>>>(
            unembW, VOCAB_, c*CH, z0, wun, KDIM, z0);
        gemm_bf16<128,128,false,true,false,false,false>
            <<<dim3(CH/128, 16, 1), 256, 0, stream>>>(
            hf, wun, unembB + c*CH, outF + c*CH, KDIM, KDIM, KDIM, VOCAB_,
            z0,z0,z0,z0,z0,z0, 1, 1.0f);
    }
}